// Round 11
// baseline (164.166 us; speedup 1.0000x reference)
//
#include <hip/hip_runtime.h>
#include <cstdint>

typedef _Float16 f16;
typedef _Float16 f16x2 __attribute__((ext_vector_type(2)));
typedef _Float16 f16x4 __attribute__((ext_vector_type(4)));
typedef _Float16 f16x8 __attribute__((ext_vector_type(8)));
typedef float f32x4 __attribute__((ext_vector_type(4)));

#define AS1U const __attribute__((address_space(1))) unsigned int
#define AS3U __attribute__((address_space(3))) unsigned int

__device__ __forceinline__ void gload_lds16(const void* g, void* l) {
    __builtin_amdgcn_global_load_lds((AS1U*)g, (AS3U*)l, 16, 0, 0);
}

// wave-local LDS sync: HGCN reduction state is per-wave (64 lanes, lockstep)
#define WSYNC() asm volatile("s_waitcnt lgkmcnt(0)" ::: "memory")
#define CFENCE() asm volatile("" ::: "memory")

#define BATCH 16384
#define NAG   32
#define OBS   96
#define SDIM  1024
#define NE    64
#define HIDN  256
#define NH    1024

// k_front grid layout (conv + packs)
#define NB_ST 1024
#define NB_PW 256
#define NB_SM 101
#define NB_FRONT (NB_ST + NB_PW + NB_SM)

// ======================= K_FRONT: states conv + weight packs =======================
__global__ __launch_bounds__(256) void k_front(
    const float* __restrict__ states,
    const float* __restrict__ w1a, const float* __restrict__ w1b,
    const float* __restrict__ w1c, const float* __restrict__ w1d,
    const float* __restrict__ b1a, const float* __restrict__ b1b,
    const float* __restrict__ b1c, const float* __restrict__ b1d,
    const float* __restrict__ w2a, const float* __restrict__ w2b,
    const float* __restrict__ w2c, const float* __restrict__ w2d,
    f16* __restrict__ states16, f16* __restrict__ W1t, float* __restrict__ b1cat,
    f16* __restrict__ W2t, f16* __restrict__ hcw2) {
    __shared__ float tile[64 * 65];
    const int tid = threadIdx.x;
    int bid = blockIdx.x;

    if (bid < NB_ST) {                    // states fp32 -> fp16
        int i = bid * 256 + tid;
        const int n4 = BATCH * SDIM / 4;
        const int stride = NB_ST * 256;
        for (; i < n4; i += stride) {
            float4 v = ((const float4*)states)[i];
            f16x4 h = { (f16)v.x, (f16)v.y, (f16)v.z, (f16)v.w };
            ((f16x4*)states16)[i] = h;
        }
        return;
    }
    bid -= NB_ST;
    if (bid < NB_PW) {                    // W1 pack via LDS transpose (coalesced both sides)
        int mlp = bid >> 6, rem = bid & 63, kt = rem >> 2, ct = rem & 3;
        const float* src = (mlp == 0) ? w1a : (mlp == 1) ? w1b : (mlp == 2) ? w1c : w1d;
        int k0 = kt * 64, c0 = ct * 64;
        for (int i = tid; i < 4096; i += 256) {
            int kk = i >> 6, cc = i & 63;
            tile[kk * 65 + cc] = src[(size_t)(k0 + kk) * 256 + c0 + cc];
        }
        __syncthreads();
        for (int i = tid; i < 4096; i += 256) {
            int cc = i >> 6, kk = i & 63;
            W1t[(size_t)(mlp * 256 + c0 + cc) * 1024 + k0 + kk] = (f16)tile[kk * 65 + cc];
        }
        return;
    }
    bid -= NB_PW;
    {                                     // W2t, hcw2, b1cat
        int i = bid * 256 + tid;
        if (i < 24576) {
            int mp = i >> 13, rem = i & 8191, oo = rem >> 8, kk = rem & 255;
            const float* src = (mp == 0) ? w2a : (mp == 1) ? w2b : w2c;
            W2t[i] = (f16)src[kk * 32 + oo];
        } else if (i < 24832) {
            int k = i - 24576;
            hcw2[k] = (f16)w2d[k];
        } else if (i < 25856) {
            int n = i - 24832;
            int mlp = n >> 8, c = n & 255;
            const float* bsrc = (mlp == 0) ? b1a : (mlp == 1) ? b1b : (mlp == 2) ? b1c : b1d;
            b1cat[n] = bsrc[c];
        }
    }
}

// ======================= K_GEMM: 256x256, 4-quadrant phase interleave (R8) =======================
__global__ __launch_bounds__(512) void k_gemm(
    const f16* __restrict__ A, const f16* __restrict__ B,
    const float* __restrict__ b1cat, const f16* __restrict__ W2t,
    const f16* __restrict__ hcw2, float* __restrict__ Pp) {
    __shared__ __align__(16) char smem[131072];
    f16* Asb = (f16*)smem;
    f16* Bsb = (f16*)(smem + 65536);
    f16* Ts  = (f16*)smem;

    const int tid = threadIdx.x;
    const int w = tid >> 6, l = tid & 63;
    const int lm = l & 15, lk = l >> 4;
    const int wm = w >> 2, wn = w & 3;
    const int p = blockIdx.x;
    const int xcd = p & 7, s = p >> 3;
    const int mt = xcd * 8 + (s >> 2);
    const int nt = s & 3;
    const int m0 = mt * 256, n0 = nt * 256;
    const int c0 = w * 4;
    const int srow = l >> 3;
    const int gchunk = (l & 7) ^ srow;

    float bj[4];
    #pragma unroll
    for (int j = 0; j < 4; j++) bj[j] = b1cat[n0 + wn * 64 + j * 16 + lm];

    f32x4 acc[8][4];
    #pragma unroll
    for (int i = 0; i < 8; i++)
        #pragma unroll
        for (int j = 0; j < 4; j++) acc[i][j] = (f32x4){0.f, 0.f, 0.f, 0.f};

#define STAGE(KT, BI)                                                                     \
    {                                                                                     \
        f16* Ad = Asb + (BI) * 16384;                                                     \
        f16* Bd = Bsb + (BI) * 16384;                                                     \
        _Pragma("unroll")                                                                 \
        for (int i_ = 0; i_ < 4; i_++) {                                                  \
            int cc = c0 + i_;                                                             \
            gload_lds16(&A[(size_t)(m0 + cc * 8 + srow) * 1024 + (KT) * 64 + gchunk * 8], \
                        &Ad[cc * 512]);                                                   \
            gload_lds16(&B[(size_t)(n0 + cc * 8 + srow) * 1024 + (KT) * 64 + gchunk * 8], \
                        &Bd[cc * 512]);                                                   \
        }                                                                                 \
    }

    STAGE(0, 0);
    STAGE(1, 1);

    for (int kt = 0; kt < 16; kt++) {
        if (kt < 15) { asm volatile("s_waitcnt vmcnt(8)" ::: "memory"); }
        else         { asm volatile("s_waitcnt vmcnt(0)" ::: "memory"); }
        CFENCE(); __builtin_amdgcn_s_barrier(); CFENCE();

        const f16* As_ = Asb + (kt & 1) * 16384;
        const f16* Bs_ = Bsb + (kt & 1) * 16384;
        const int swlo = ((lk ^ (lm & 7)) << 3);
        const int swhi = (((4 + lk) ^ (lm & 7)) << 3);

        f16x8 af[4][2], bf01[2][2], bf23[2][2];

        // ---- phase A ----
        #pragma unroll
        for (int i = 0; i < 4; i++) {
            af[i][0] = *(const f16x8*)&As_[(wm * 128 + i * 16 + lm) * 64 + swlo];
            af[i][1] = *(const f16x8*)&As_[(wm * 128 + i * 16 + lm) * 64 + swhi];
        }
        #pragma unroll
        for (int j = 0; j < 2; j++) {
            bf01[j][0] = *(const f16x8*)&Bs_[(wn * 64 + j * 16 + lm) * 64 + swlo];
            bf01[j][1] = *(const f16x8*)&Bs_[(wn * 64 + j * 16 + lm) * 64 + swhi];
        }
        __builtin_amdgcn_s_setprio(1);
        #pragma unroll
        for (int ks = 0; ks < 2; ks++)
            #pragma unroll
            for (int i = 0; i < 4; i++)
                #pragma unroll
                for (int j = 0; j < 2; j++)
                    acc[i][j] = __builtin_amdgcn_mfma_f32_16x16x32_f16(af[i][ks], bf01[j][ks], acc[i][j], 0, 0, 0);
        __builtin_amdgcn_s_setprio(0);
        CFENCE(); __builtin_amdgcn_s_barrier(); CFENCE();

        // ---- phase B ----
        #pragma unroll
        for (int j = 0; j < 2; j++) {
            bf23[j][0] = *(const f16x8*)&Bs_[(wn * 64 + (2 + j) * 16 + lm) * 64 + swlo];
            bf23[j][1] = *(const f16x8*)&Bs_[(wn * 64 + (2 + j) * 16 + lm) * 64 + swhi];
        }
        __builtin_amdgcn_s_setprio(1);
        #pragma unroll
        for (int ks = 0; ks < 2; ks++)
            #pragma unroll
            for (int i = 0; i < 4; i++)
                #pragma unroll
                for (int j = 0; j < 2; j++)
                    acc[i][2 + j] = __builtin_amdgcn_mfma_f32_16x16x32_f16(af[i][ks], bf23[j][ks], acc[i][2 + j], 0, 0, 0);
        __builtin_amdgcn_s_setprio(0);
        CFENCE(); __builtin_amdgcn_s_barrier(); CFENCE();

        // ---- phase C ----
        #pragma unroll
        for (int i = 0; i < 4; i++) {
            af[i][0] = *(const f16x8*)&As_[(wm * 128 + (4 + i) * 16 + lm) * 64 + swlo];
            af[i][1] = *(const f16x8*)&As_[(wm * 128 + (4 + i) * 16 + lm) * 64 + swhi];
        }
        __builtin_amdgcn_s_setprio(1);
        #pragma unroll
        for (int ks = 0; ks < 2; ks++)
            #pragma unroll
            for (int i = 0; i < 4; i++)
                #pragma unroll
                for (int j = 0; j < 2; j++)
                    acc[4 + i][j] = __builtin_amdgcn_mfma_f32_16x16x32_f16(af[i][ks], bf01[j][ks], acc[4 + i][j], 0, 0, 0);
        __builtin_amdgcn_s_setprio(0);
        CFENCE(); __builtin_amdgcn_s_barrier(); CFENCE();

        // ---- phase D ----
        if (kt < 14) STAGE(kt + 2, kt & 1);
        __builtin_amdgcn_s_setprio(1);
        #pragma unroll
        for (int ks = 0; ks < 2; ks++)
            #pragma unroll
            for (int i = 0; i < 4; i++)
                #pragma unroll
                for (int j = 0; j < 2; j++)
                    acc[4 + i][2 + j] = __builtin_amdgcn_mfma_f32_16x16x32_f16(af[i][ks], bf23[j][ks], acc[4 + i][2 + j], 0, 0, 0);
        __builtin_amdgcn_s_setprio(0);
    }
#undef STAGE

    __syncthreads();

    const int mlp = nt;
    #pragma unroll
    for (int pass = 0; pass < 2; pass++) {
        if (wm == pass) {
            #pragma unroll
            for (int i = 0; i < 8; i++)
                #pragma unroll
                for (int r = 0; r < 4; r++) {
                    int rl = i * 16 + lk * 4 + r;
                    #pragma unroll
                    for (int j = 0; j < 4; j++) {
                        float v = acc[i][j][r] + bj[j];
                        Ts[rl * 264 + wn * 64 + j * 16 + lm] = (f16)(v > 0.f ? v : 0.f);
                    }
                }
        }
        __syncthreads();
        const int grow = m0 + pass * 128 + w * 16;
        if (mlp < 3) {
            const f16* wb = W2t + mlp * 8192;
            f32x4 acc2[2];
            acc2[0] = (f32x4){0, 0, 0, 0}; acc2[1] = (f32x4){0, 0, 0, 0};
            #pragma unroll
            for (int ks = 0; ks < 8; ks++) {
                f16x8 a  = *(const f16x8*)&Ts[(w * 16 + lm) * 264 + ks * 32 + lk * 8];
                f16x8 b0 = *(const f16x8*)&wb[lm * 256 + ks * 32 + lk * 8];
                f16x8 b1 = *(const f16x8*)&wb[(16 + lm) * 256 + ks * 32 + lk * 8];
                acc2[0] = __builtin_amdgcn_mfma_f32_16x16x32_f16(a, b0, acc2[0], 0, 0, 0);
                acc2[1] = __builtin_amdgcn_mfma_f32_16x16x32_f16(a, b1, acc2[1], 0, 0, 0);
            }
            #pragma unroll
            for (int j2 = 0; j2 < 2; j2++)
                #pragma unroll
                for (int r = 0; r < 4; r++)
                    Pp[(size_t)(grow + lk * 4 + r) * 104 + mlp * 32 + j2 * 16 + lm] = acc2[j2][r];
        } else {
            f32x4 acc2 = (f32x4){0, 0, 0, 0};
            #pragma unroll
            for (int ks = 0; ks < 8; ks++) {
                f16x8 a = *(const f16x8*)&Ts[(w * 16 + lm) * 264 + ks * 32 + lk * 8];
                f16x8 bz = (f16x8){0, 0, 0, 0, 0, 0, 0, 0};
                if (lm == 0) bz = *(const f16x8*)&hcw2[ks * 32 + lk * 8];
                acc2 = __builtin_amdgcn_mfma_f32_16x16x32_f16(a, bz, acc2, 0, 0, 0);
            }
            if (lm == 0)
                #pragma unroll
                for (int r = 0; r < 4; r++)
                    Pp[(size_t)(grow + lk * 4 + r) * 104 + 96] = acc2[r];
        }
        if (pass == 0) __syncthreads();
    }
}

// ======================= K_HGCN_EP: HGCN + fused mix epilogue (R8 version) =======================
__global__ __launch_bounds__(256) void k_hgcn_ep(
    const float* __restrict__ agent_qs, const float* __restrict__ indiv_us,
    const float* __restrict__ edge_W, const float* __restrict__ edge_b,
    const float* __restrict__ wline1, const float* __restrict__ wline2,
    const float* __restrict__ Pp,
    const float* __restrict__ hw1_b2, const float* __restrict__ hc1_b2,
    const float* __restrict__ hw_b2, const float* __restrict__ hc_b2,
    float* __restrict__ out) {
    __shared__ __align__(16) char arena[34304];
    f16*   eWs   = (f16*)arena;
    float* swa   = (float*)(arena + 13312);
    f16*   HsB   = (f16*)(arena + 13824);
    float* svB   = (float*)(arena + 30720);
    float* sttB  = (float*)(arena + 31744);
    float* sdisB = (float*)(arena + 32256);
    float* sbinvB= (float*)(arena + 33280);

    const int tid = threadIdx.x;
    const int w = tid >> 6, l = tid & 63;
    const int b = blockIdx.x * 4 + w;
    f16*   Hw    = HsB + w * (32 * 66);
    float* sv    = svB + w * 64;
    float* stt   = sttB + w * 32;
    float* sdis  = sdisB + w * 64;
    float* sbinv = sbinvB + w * 64;

    const int nn = l & 31, half = l >> 5;

    float pa0 = 0.f, pc0 = 0.f, pw0 = 0.f;
    float p96a = 0.f, bw1 = 0.f, bc1 = 0.f, bww = 0.f, bhc = 0.f;
    if (half == 0) {
        const float* p0 = Pp + (size_t)b * 104;
        pa0 = p0[nn];
        pc0 = p0[32 + nn];
        pw0 = p0[64 + nn];
        p96a = p0[96];
        bw1 = hw1_b2[nn];  bc1 = hc1_b2[nn];
        bww = hw_b2[nn];   bhc = hc_b2[0];
    }
    float q = agent_qs[(size_t)b * 32 + nn];

    for (int i = tid; i < 6144; i += 256) {
        int k = i >> 6, n = i & 63;
        eWs[n * 104 + k] = (f16)edge_W[i];
    }
    if (tid < 64) swa[tid] = fabsf(wline1[tid]);
    else if (tid < 128) swa[tid] = fabsf(wline2[tid - 64]);
    __syncthreads();

    const int lm = l & 15, lk = l >> 4;
    const float* ub = indiv_us + (size_t)b * (NAG * OBS);

    #pragma unroll
    for (int mt = 0; mt < 2; mt++) {
        f16x8 af[3];
        #pragma unroll
        for (int ks = 0; ks < 3; ks++) {
            const float* up = ub + (mt * 16 + lm) * 96 + ks * 32 + lk * 8;
            float4 v0 = *(const float4*)up;
            float4 v1 = *(const float4*)(up + 4);
            af[ks] = (f16x8){ (f16)v0.x, (f16)v0.y, (f16)v0.z, (f16)v0.w,
                              (f16)v1.x, (f16)v1.y, (f16)v1.z, (f16)v1.w };
        }
        #pragma unroll
        for (int nt = 0; nt < 4; nt++) {
            f32x4 acc = {0.f, 0.f, 0.f, 0.f};
            #pragma unroll
            for (int ks = 0; ks < 3; ks++) {
                f16x8 bb = *(const f16x8*)&eWs[(nt * 16 + lm) * 104 + ks * 32 + lk * 8];
                acc = __builtin_amdgcn_mfma_f32_16x16x32_f16(af[ks], bb, acc, 0, 0, 0);
            }
            int col = nt * 16 + lm;
            float bias = edge_b[col];
            #pragma unroll
            for (int r = 0; r < 4; r++) {
                int row = mt * 16 + lk * 4 + r;
                float hv = acc[r] + bias;
                Hw[row * 66 + col] = (f16)(hv > 0.f ? hv : 0.f);
            }
        }
    }
    WSYNC();

    float bsum = 0.f;
    #pragma unroll
    for (int n = 0; n < 32; n++) bsum += (float)Hw[n * 66 + l];
    sbinv[l] = bsum > 0.f ? 1.f / bsum : 0.f;

    float dd = 0.f;
    #pragma unroll 8
    for (int e2 = 0; e2 < 32; e2++) {
        f16x2 h2 = *(const f16x2*)&Hw[nn * 66 + e2 * 2];
        dd += (float)h2.x * swa[half * 64 + e2 * 2] + (float)h2.y * swa[half * 64 + e2 * 2 + 1];
    }
    float dis = dd > 0.f ? rsqrtf(dd) : 0.f;
    sdis[l] = dis;
    if (half == 0) stt[nn] = dis * q;
    WSYNC();

    float s1 = 0.f;
    #pragma unroll
    for (int n = 0; n < 32; n++) s1 += (float)Hw[n * 66 + l] * stt[n];
    sv[l] = s1 * swa[l] * sbinv[l];
    WSYNC();

    float y1 = 0.f;
    #pragma unroll 8
    for (int e2 = 0; e2 < 32; e2++) {
        f16x2 h2 = *(const f16x2*)&Hw[nn * 66 + e2 * 2];
        y1 += (float)h2.x * sv[e2 * 2] + (float)h2.y * sv[e2 * 2 + 1];
    }
    float x2 = sdis[nn] * y1;
    if (half == 0) stt[nn] = sdis[32 + nn] * x2;
    WSYNC();

    float s2 = 0.f;
    #pragma unroll
    for (int n = 0; n < 32; n++) s2 += (float)Hw[n * 66 + l] * stt[n];
    sv[l] = s2 * swa[64 + l] * sbinv[l];
    WSYNC();

    float y2 = 0.f;
    #pragma unroll 8
    for (int e2 = 0; e2 < 32; e2++) {
        f16x2 h2 = *(const f16x2*)&Hw[nn * 66 + e2 * 2];
        y2 += (float)h2.x * sv[e2 * 2] + (float)h2.y * sv[e2 * 2 + 1];
    }

    float qsv = sdis[32 + nn] * y2;
    float w1v = fabsf(pa0 + bw1);
    float c1v = pc0 + bc1;
    float wwv = fabsf(pw0 + bww);
    float z = qsv * w1v + c1v;
    float qt = z > 0.f ? z : expm1f(z);
    float val = (half == 0) ? qt * wwv : 0.f;
    val += __shfl_xor(val, 1, 32);
    val += __shfl_xor(val, 2, 32);
    val += __shfl_xor(val, 4, 32);
    val += __shfl_xor(val, 8, 32);
    val += __shfl_xor(val, 16, 32);
    if (l == 0) out[b] = val + p96a + bhc;
}

// ======================= launch =======================
extern "C" void kernel_launch(void* const* d_in, const int* in_sizes, int n_in,
                              void* d_out, int out_size, void* d_ws, size_t ws_size,
                              hipStream_t stream) {
    const float* agent_qs = (const float*)d_in[0];
    const float* states   = (const float*)d_in[1];
    const float* indiv_us = (const float*)d_in[2];
    const float* edge_W   = (const float*)d_in[3];
    const float* edge_b   = (const float*)d_in[4];
    const float* wline1   = (const float*)d_in[5];
    const float* wline2   = (const float*)d_in[6];
    const float* hw1_w1 = (const float*)d_in[7];
    const float* hw1_b1 = (const float*)d_in[8];
    const float* hw1_w2 = (const float*)d_in[9];
    const float* hw1_b2 = (const float*)d_in[10];
    const float* hc1_w1 = (const float*)d_in[11];
    const float* hc1_b1 = (const float*)d_in[12];
    const float* hc1_w2 = (const float*)d_in[13];
    const float* hc1_b2 = (const float*)d_in[14];
    const float* hw_w1  = (const float*)d_in[15];
    const float* hw_b1  = (const float*)d_in[16];
    const float* hw_w2  = (const float*)d_in[17];
    const float* hw_b2  = (const float*)d_in[18];
    const float* hc_w1  = (const float*)d_in[19];
    const float* hc_b1  = (const float*)d_in[20];
    const float* hc_w2  = (const float*)d_in[21];
    const float* hc_b2  = (const float*)d_in[22];

    char* ws = (char*)d_ws;
    size_t o_states16 = 0;                                   // 33,554,432
    size_t o_W1t  = o_states16 + (size_t)BATCH * SDIM * 2;   // 2,097,152
    size_t o_b1   = o_W1t + (size_t)NH * SDIM * 2;           // 4096
    size_t o_W2t  = o_b1 + 4096;                             // 49,152
    size_t o_hcw2 = o_W2t + 49152;                           // 512
    size_t o_Pp   = o_hcw2 + 512;                            // 16384*104*4 = 6.8MB

    f16*   states16 = (f16*)(ws + o_states16);
    f16*   W1t      = (f16*)(ws + o_W1t);
    float* b1cat    = (float*)(ws + o_b1);
    f16*   W2t      = (f16*)(ws + o_W2t);
    f16*   hcw2     = (f16*)(ws + o_hcw2);
    float* Pp       = (float*)(ws + o_Pp);

    k_front<<<NB_FRONT, 256, 0, stream>>>(
        states,
        hw1_w1, hc1_w1, hw_w1, hc_w1, hw1_b1, hc1_b1, hw_b1, hc_b1,
        hw1_w2, hc1_w2, hw_w2, hc_w2,
        states16, W1t, b1cat, W2t, hcw2);
    k_gemm<<<256, 512, 0, stream>>>(states16, W1t, b1cat, W2t, hcw2, Pp);
    // === attribution probe: k_hgcn_ep launched TWICE (idempotent) ===
    // dur_us(R11) - 120.4 = marginal cost of one hgcn_ep dispatch (L3-warm-biased low).
    k_hgcn_ep<<<BATCH / 4, 256, 0, stream>>>(
        agent_qs, indiv_us, edge_W, edge_b, wline1, wline2, Pp,
        hw1_b2, hc1_b2, hw_b2, hc_b2, (float*)d_out);
    k_hgcn_ep<<<BATCH / 4, 256, 0, stream>>>(
        agent_qs, indiv_us, edge_W, edge_b, wline1, wline2, Pp,
        hw1_b2, hc1_b2, hw_b2, hc_b2, (float*)d_out);
}

// Round 12
// 131.490 us; speedup vs baseline: 1.2485x; 1.2485x over previous
//
#include <hip/hip_runtime.h>
#include <cstdint>

typedef _Float16 f16;
typedef _Float16 f16x2 __attribute__((ext_vector_type(2)));
typedef _Float16 f16x4 __attribute__((ext_vector_type(4)));
typedef _Float16 f16x8 __attribute__((ext_vector_type(8)));
typedef float f32x4 __attribute__((ext_vector_type(4)));

#define AS1U const __attribute__((address_space(1))) unsigned int
#define AS3U __attribute__((address_space(3))) unsigned int

__device__ __forceinline__ void gload_lds16(const void* g, void* l) {
    __builtin_amdgcn_global_load_lds((AS1U*)g, (AS3U*)l, 16, 0, 0);
}

// wave-local LDS sync: HGCN reduction state is per-wave (64 lanes, lockstep)
#define WSYNC() asm volatile("s_waitcnt lgkmcnt(0)" ::: "memory")
#define CFENCE() asm volatile("" ::: "memory")

#define BATCH 16384
#define NAG   32
#define OBS   96
#define SDIM  1024
#define NE    64
#define HIDN  256
#define NH    1024

// k_front grid layout (conv + packs)
#define NB_ST 1024
#define NB_PW 256
#define NB_SM 101
#define NB_FRONT (NB_ST + NB_PW + NB_SM)

// ======================= K_FRONT: states conv + weight packs =======================
__global__ __launch_bounds__(256) void k_front(
    const float* __restrict__ states,
    const float* __restrict__ w1a, const float* __restrict__ w1b,
    const float* __restrict__ w1c, const float* __restrict__ w1d,
    const float* __restrict__ b1a, const float* __restrict__ b1b,
    const float* __restrict__ b1c, const float* __restrict__ b1d,
    const float* __restrict__ w2a, const float* __restrict__ w2b,
    const float* __restrict__ w2c, const float* __restrict__ w2d,
    f16* __restrict__ states16, f16* __restrict__ W1t, float* __restrict__ b1cat,
    f16* __restrict__ W2t, f16* __restrict__ hcw2) {
    __shared__ float tile[64 * 65];
    const int tid = threadIdx.x;
    int bid = blockIdx.x;

    if (bid < NB_ST) {                    // states fp32 -> fp16
        int i = bid * 256 + tid;
        const int n4 = BATCH * SDIM / 4;
        const int stride = NB_ST * 256;
        for (; i < n4; i += stride) {
            float4 v = ((const float4*)states)[i];
            f16x4 h = { (f16)v.x, (f16)v.y, (f16)v.z, (f16)v.w };
            ((f16x4*)states16)[i] = h;
        }
        return;
    }
    bid -= NB_ST;
    if (bid < NB_PW) {                    // W1 pack via LDS transpose (coalesced both sides)
        int mlp = bid >> 6, rem = bid & 63, kt = rem >> 2, ct = rem & 3;
        const float* src = (mlp == 0) ? w1a : (mlp == 1) ? w1b : (mlp == 2) ? w1c : w1d;
        int k0 = kt * 64, c0 = ct * 64;
        for (int i = tid; i < 4096; i += 256) {
            int kk = i >> 6, cc = i & 63;
            tile[kk * 65 + cc] = src[(size_t)(k0 + kk) * 256 + c0 + cc];
        }
        __syncthreads();
        for (int i = tid; i < 4096; i += 256) {
            int cc = i >> 6, kk = i & 63;
            W1t[(size_t)(mlp * 256 + c0 + cc) * 1024 + k0 + kk] = (f16)tile[kk * 65 + cc];
        }
        return;
    }
    bid -= NB_PW;
    {                                     // W2t, hcw2, b1cat
        int i = bid * 256 + tid;
        if (i < 24576) {
            int mp = i >> 13, rem = i & 8191, oo = rem >> 8, kk = rem & 255;
            const float* src = (mp == 0) ? w2a : (mp == 1) ? w2b : w2c;
            W2t[i] = (f16)src[kk * 32 + oo];
        } else if (i < 24832) {
            int k = i - 24576;
            hcw2[k] = (f16)w2d[k];
        } else if (i < 25856) {
            int n = i - 24832;
            int mlp = n >> 8, c = n & 255;
            const float* bsrc = (mlp == 0) ? b1a : (mlp == 1) ? b1b : (mlp == 2) ? b1c : b1d;
            b1cat[n] = bsrc[c];
        }
    }
}

// ======================= K_GEMM: 256x256, 4-quadrant phase interleave (R8) =======================
__global__ __launch_bounds__(512) void k_gemm(
    const f16* __restrict__ A, const f16* __restrict__ B,
    const float* __restrict__ b1cat, const f16* __restrict__ W2t,
    const f16* __restrict__ hcw2, float* __restrict__ Pp) {
    __shared__ __align__(16) char smem[131072];
    f16* Asb = (f16*)smem;
    f16* Bsb = (f16*)(smem + 65536);
    f16* Ts  = (f16*)smem;

    const int tid = threadIdx.x;
    const int w = tid >> 6, l = tid & 63;
    const int lm = l & 15, lk = l >> 4;
    const int wm = w >> 2, wn = w & 3;
    const int p = blockIdx.x;
    const int xcd = p & 7, s = p >> 3;
    const int mt = xcd * 8 + (s >> 2);
    const int nt = s & 3;
    const int m0 = mt * 256, n0 = nt * 256;
    const int c0 = w * 4;
    const int srow = l >> 3;
    const int gchunk = (l & 7) ^ srow;

    float bj[4];
    #pragma unroll
    for (int j = 0; j < 4; j++) bj[j] = b1cat[n0 + wn * 64 + j * 16 + lm];

    f32x4 acc[8][4];
    #pragma unroll
    for (int i = 0; i < 8; i++)
        #pragma unroll
        for (int j = 0; j < 4; j++) acc[i][j] = (f32x4){0.f, 0.f, 0.f, 0.f};

#define STAGE(KT, BI)                                                                     \
    {                                                                                     \
        f16* Ad = Asb + (BI) * 16384;                                                     \
        f16* Bd = Bsb + (BI) * 16384;                                                     \
        _Pragma("unroll")                                                                 \
        for (int i_ = 0; i_ < 4; i_++) {                                                  \
            int cc = c0 + i_;                                                             \
            gload_lds16(&A[(size_t)(m0 + cc * 8 + srow) * 1024 + (KT) * 64 + gchunk * 8], \
                        &Ad[cc * 512]);                                                   \
            gload_lds16(&B[(size_t)(n0 + cc * 8 + srow) * 1024 + (KT) * 64 + gchunk * 8], \
                        &Bd[cc * 512]);                                                   \
        }                                                                                 \
    }

    STAGE(0, 0);
    STAGE(1, 1);

    for (int kt = 0; kt < 16; kt++) {
        if (kt < 15) { asm volatile("s_waitcnt vmcnt(8)" ::: "memory"); }
        else         { asm volatile("s_waitcnt vmcnt(0)" ::: "memory"); }
        CFENCE(); __builtin_amdgcn_s_barrier(); CFENCE();

        const f16* As_ = Asb + (kt & 1) * 16384;
        const f16* Bs_ = Bsb + (kt & 1) * 16384;
        const int swlo = ((lk ^ (lm & 7)) << 3);
        const int swhi = (((4 + lk) ^ (lm & 7)) << 3);

        f16x8 af[4][2], bf01[2][2], bf23[2][2];

        // ---- phase A ----
        #pragma unroll
        for (int i = 0; i < 4; i++) {
            af[i][0] = *(const f16x8*)&As_[(wm * 128 + i * 16 + lm) * 64 + swlo];
            af[i][1] = *(const f16x8*)&As_[(wm * 128 + i * 16 + lm) * 64 + swhi];
        }
        #pragma unroll
        for (int j = 0; j < 2; j++) {
            bf01[j][0] = *(const f16x8*)&Bs_[(wn * 64 + j * 16 + lm) * 64 + swlo];
            bf01[j][1] = *(const f16x8*)&Bs_[(wn * 64 + j * 16 + lm) * 64 + swhi];
        }
        __builtin_amdgcn_s_setprio(1);
        #pragma unroll
        for (int ks = 0; ks < 2; ks++)
            #pragma unroll
            for (int i = 0; i < 4; i++)
                #pragma unroll
                for (int j = 0; j < 2; j++)
                    acc[i][j] = __builtin_amdgcn_mfma_f32_16x16x32_f16(af[i][ks], bf01[j][ks], acc[i][j], 0, 0, 0);
        __builtin_amdgcn_s_setprio(0);
        CFENCE(); __builtin_amdgcn_s_barrier(); CFENCE();

        // ---- phase B ----
        #pragma unroll
        for (int j = 0; j < 2; j++) {
            bf23[j][0] = *(const f16x8*)&Bs_[(wn * 64 + (2 + j) * 16 + lm) * 64 + swlo];
            bf23[j][1] = *(const f16x8*)&Bs_[(wn * 64 + (2 + j) * 16 + lm) * 64 + swhi];
        }
        __builtin_amdgcn_s_setprio(1);
        #pragma unroll
        for (int ks = 0; ks < 2; ks++)
            #pragma unroll
            for (int i = 0; i < 4; i++)
                #pragma unroll
                for (int j = 0; j < 2; j++)
                    acc[i][2 + j] = __builtin_amdgcn_mfma_f32_16x16x32_f16(af[i][ks], bf23[j][ks], acc[i][2 + j], 0, 0, 0);
        __builtin_amdgcn_s_setprio(0);
        CFENCE(); __builtin_amdgcn_s_barrier(); CFENCE();

        // ---- phase C ----
        #pragma unroll
        for (int i = 0; i < 4; i++) {
            af[i][0] = *(const f16x8*)&As_[(wm * 128 + (4 + i) * 16 + lm) * 64 + swlo];
            af[i][1] = *(const f16x8*)&As_[(wm * 128 + (4 + i) * 16 + lm) * 64 + swhi];
        }
        __builtin_amdgcn_s_setprio(1);
        #pragma unroll
        for (int ks = 0; ks < 2; ks++)
            #pragma unroll
            for (int i = 0; i < 4; i++)
                #pragma unroll
                for (int j = 0; j < 2; j++)
                    acc[4 + i][j] = __builtin_amdgcn_mfma_f32_16x16x32_f16(af[i][ks], bf01[j][ks], acc[4 + i][j], 0, 0, 0);
        __builtin_amdgcn_s_setprio(0);
        CFENCE(); __builtin_amdgcn_s_barrier(); CFENCE();

        // ---- phase D ----
        if (kt < 14) STAGE(kt + 2, kt & 1);
        __builtin_amdgcn_s_setprio(1);
        #pragma unroll
        for (int ks = 0; ks < 2; ks++)
            #pragma unroll
            for (int i = 0; i < 4; i++)
                #pragma unroll
                for (int j = 0; j < 2; j++)
                    acc[4 + i][2 + j] = __builtin_amdgcn_mfma_f32_16x16x32_f16(af[i][ks], bf23[j][ks], acc[4 + i][2 + j], 0, 0, 0);
        __builtin_amdgcn_s_setprio(0);
    }
#undef STAGE

    __syncthreads();

    const int mlp = nt;
    #pragma unroll
    for (int pass = 0; pass < 2; pass++) {
        if (wm == pass) {
            #pragma unroll
            for (int i = 0; i < 8; i++)
                #pragma unroll
                for (int r = 0; r < 4; r++) {
                    int rl = i * 16 + lk * 4 + r;
                    #pragma unroll
                    for (int j = 0; j < 4; j++) {
                        float v = acc[i][j][r] + bj[j];
                        Ts[rl * 264 + wn * 64 + j * 16 + lm] = (f16)(v > 0.f ? v : 0.f);
                    }
                }
        }
        __syncthreads();
        const int grow = m0 + pass * 128 + w * 16;
        if (mlp < 3) {
            const f16* wb = W2t + mlp * 8192;
            f32x4 acc2[2];
            acc2[0] = (f32x4){0, 0, 0, 0}; acc2[1] = (f32x4){0, 0, 0, 0};
            #pragma unroll
            for (int ks = 0; ks < 8; ks++) {
                f16x8 a  = *(const f16x8*)&Ts[(w * 16 + lm) * 264 + ks * 32 + lk * 8];
                f16x8 b0 = *(const f16x8*)&wb[lm * 256 + ks * 32 + lk * 8];
                f16x8 b1 = *(const f16x8*)&wb[(16 + lm) * 256 + ks * 32 + lk * 8];
                acc2[0] = __builtin_amdgcn_mfma_f32_16x16x32_f16(a, b0, acc2[0], 0, 0, 0);
                acc2[1] = __builtin_amdgcn_mfma_f32_16x16x32_f16(a, b1, acc2[1], 0, 0, 0);
            }
            #pragma unroll
            for (int j2 = 0; j2 < 2; j2++)
                #pragma unroll
                for (int r = 0; r < 4; r++)
                    Pp[(size_t)(grow + lk * 4 + r) * 104 + mlp * 32 + j2 * 16 + lm] = acc2[j2][r];
        } else {
            f32x4 acc2 = (f32x4){0, 0, 0, 0};
            #pragma unroll
            for (int ks = 0; ks < 8; ks++) {
                f16x8 a = *(const f16x8*)&Ts[(w * 16 + lm) * 264 + ks * 32 + lk * 8];
                f16x8 bz = (f16x8){0, 0, 0, 0, 0, 0, 0, 0};
                if (lm == 0) bz = *(const f16x8*)&hcw2[ks * 32 + lk * 8];
                acc2 = __builtin_amdgcn_mfma_f32_16x16x32_f16(a, bz, acc2, 0, 0, 0);
            }
            if (lm == 0)
                #pragma unroll
                for (int r = 0; r < 4; r++)
                    Pp[(size_t)(grow + lk * 4 + r) * 104 + 96] = acc2[r];
        }
        if (pass == 0) __syncthreads();
    }
}

// ======================= K_HGCN_EP: 4 batches/wave, cross-batch prefetch pipeline =======================
// Grid 1024 blocks; wave w handles batches blk*16 + w*4 + {0..3}. eWs staging amortized 4x.
// Batch-0 u/Pp loads issue BEFORE eWs staging+barrier; batch it+1's loads issue right after
// batch it's u registers are consumed (conversion) — HBM latency hides under the reduction chain.
// Arithmetic identical to R8.
__global__ __launch_bounds__(256) void k_hgcn_ep(
    const float* __restrict__ agent_qs, const float* __restrict__ indiv_us,
    const float* __restrict__ edge_W, const float* __restrict__ edge_b,
    const float* __restrict__ wline1, const float* __restrict__ wline2,
    const float* __restrict__ Pp,
    const float* __restrict__ hw1_b2, const float* __restrict__ hc1_b2,
    const float* __restrict__ hw_b2, const float* __restrict__ hc_b2,
    float* __restrict__ out) {
    __shared__ __align__(16) char arena[34304];
    f16*   eWs   = (f16*)arena;
    float* swa   = (float*)(arena + 13312);
    f16*   HsB   = (f16*)(arena + 13824);
    float* svB   = (float*)(arena + 30720);
    float* sttB  = (float*)(arena + 31744);
    float* sdisB = (float*)(arena + 32256);
    float* sbinvB= (float*)(arena + 33280);

    const int tid = threadIdx.x;
    const int w = tid >> 6, l = tid & 63;
    const int b0 = blockIdx.x * 16 + w * 4;     // this wave's first batch
    f16*   Hw    = HsB + w * (32 * 66);
    float* sv    = svB + w * 64;
    float* stt   = sttB + w * 32;
    float* sdis  = sdisB + w * 64;
    float* sbinv = sbinvB + w * 64;

    const int nn = l & 31, half = l >> 5;
    const int lm = l & 15, lk = l >> 4;

    // ---- prefetch batch 0 (u + Pp + q) BEFORE eWs staging ----
    float4 uf[2][3][2];
    {
        const float* ub = indiv_us + (size_t)b0 * (NAG * OBS);
        #pragma unroll
        for (int mt = 0; mt < 2; mt++)
            #pragma unroll
            for (int ks = 0; ks < 3; ks++) {
                const float* up = ub + (mt * 16 + lm) * 96 + ks * 32 + lk * 8;
                uf[mt][ks][0] = *(const float4*)up;
                uf[mt][ks][1] = *(const float4*)(up + 4);
            }
    }
    float pa = 0.f, pc = 0.f, pw = 0.f, p96 = 0.f;
    float bw1 = 0.f, bc1 = 0.f, bww = 0.f, bhc = 0.f;
    if (half == 0) {
        const float* p0 = Pp + (size_t)b0 * 104;
        pa = p0[nn]; pc = p0[32 + nn]; pw = p0[64 + nn]; p96 = p0[96];
        bw1 = hw1_b2[nn]; bc1 = hc1_b2[nn]; bww = hw_b2[nn]; bhc = hc_b2[0];
    }
    float q = agent_qs[(size_t)b0 * 32 + nn];

    // ---- eWs / swa staging (once per block, amortized over 16 batches) ----
    for (int i = tid; i < 6144; i += 256) {
        int k = i >> 6, n = i & 63;
        eWs[n * 104 + k] = (f16)edge_W[i];
    }
    if (tid < 64) swa[tid] = fabsf(wline1[tid]);
    else if (tid < 128) swa[tid] = fabsf(wline2[tid - 64]);
    __syncthreads();   // the only block-wide barrier

    #pragma unroll
    for (int it = 0; it < 4; it++) {
        const int b = b0 + it;

        // convert current u regs -> f16 fragments (frees uf for next batch)
        f16x8 afc[2][3];
        #pragma unroll
        for (int mt = 0; mt < 2; mt++)
            #pragma unroll
            for (int ks = 0; ks < 3; ks++) {
                float4 v0 = uf[mt][ks][0], v1 = uf[mt][ks][1];
                afc[mt][ks] = (f16x8){ (f16)v0.x, (f16)v0.y, (f16)v0.z, (f16)v0.w,
                                       (f16)v1.x, (f16)v1.y, (f16)v1.z, (f16)v1.w };
            }

        // issue next batch's loads NOW (hide under this batch's MFMA + reductions)
        float pa_n = 0.f, pc_n = 0.f, pw_n = 0.f, p96_n = 0.f, q_n = 0.f;
        if (it < 3) {
            const float* ub = indiv_us + (size_t)(b + 1) * (NAG * OBS);
            #pragma unroll
            for (int mt = 0; mt < 2; mt++)
                #pragma unroll
                for (int ks = 0; ks < 3; ks++) {
                    const float* up = ub + (mt * 16 + lm) * 96 + ks * 32 + lk * 8;
                    uf[mt][ks][0] = *(const float4*)up;
                    uf[mt][ks][1] = *(const float4*)(up + 4);
                }
            if (half == 0) {
                const float* p0 = Pp + (size_t)(b + 1) * 104;
                pa_n = p0[nn]; pc_n = p0[32 + nn]; pw_n = p0[64 + nn]; p96_n = p0[96];
            }
            q_n = agent_qs[(size_t)(b + 1) * 32 + nn];
        }

        // H = relu(u @ W^T + b)
        #pragma unroll
        for (int mt = 0; mt < 2; mt++) {
            #pragma unroll
            for (int nt = 0; nt < 4; nt++) {
                f32x4 acc = {0.f, 0.f, 0.f, 0.f};
                #pragma unroll
                for (int ks = 0; ks < 3; ks++) {
                    f16x8 bb = *(const f16x8*)&eWs[(nt * 16 + lm) * 104 + ks * 32 + lk * 8];
                    acc = __builtin_amdgcn_mfma_f32_16x16x32_f16(afc[mt][ks], bb, acc, 0, 0, 0);
                }
                int col = nt * 16 + lm;
                float bias = edge_b[col];
                #pragma unroll
                for (int r = 0; r < 4; r++) {
                    int row = mt * 16 + lk * 4 + r;
                    float hv = acc[r] + bias;
                    Hw[row * 66 + col] = (f16)(hv > 0.f ? hv : 0.f);
                }
            }
        }
        WSYNC();

        float bsum = 0.f;
        #pragma unroll
        for (int n = 0; n < 32; n++) bsum += (float)Hw[n * 66 + l];
        sbinv[l] = bsum > 0.f ? 1.f / bsum : 0.f;

        float dd = 0.f;
        #pragma unroll 8
        for (int e2 = 0; e2 < 32; e2++) {
            f16x2 h2 = *(const f16x2*)&Hw[nn * 66 + e2 * 2];
            dd += (float)h2.x * swa[half * 64 + e2 * 2] + (float)h2.y * swa[half * 64 + e2 * 2 + 1];
        }
        float dis = dd > 0.f ? rsqrtf(dd) : 0.f;
        sdis[l] = dis;
        if (half == 0) stt[nn] = dis * q;
        WSYNC();

        float s1 = 0.f;
        #pragma unroll
        for (int n = 0; n < 32; n++) s1 += (float)Hw[n * 66 + l] * stt[n];
        sv[l] = s1 * swa[l] * sbinv[l];
        WSYNC();

        float y1 = 0.f;
        #pragma unroll 8
        for (int e2 = 0; e2 < 32; e2++) {
            f16x2 h2 = *(const f16x2*)&Hw[nn * 66 + e2 * 2];
            y1 += (float)h2.x * sv[e2 * 2] + (float)h2.y * sv[e2 * 2 + 1];
        }
        float x2 = sdis[nn] * y1;
        if (half == 0) stt[nn] = sdis[32 + nn] * x2;
        WSYNC();

        float s2 = 0.f;
        #pragma unroll
        for (int n = 0; n < 32; n++) s2 += (float)Hw[n * 66 + l] * stt[n];
        sv[l] = s2 * swa[64 + l] * sbinv[l];
        WSYNC();

        float y2 = 0.f;
        #pragma unroll 8
        for (int e2 = 0; e2 < 32; e2++) {
            f16x2 h2 = *(const f16x2*)&Hw[nn * 66 + e2 * 2];
            y2 += (float)h2.x * sv[e2 * 2] + (float)h2.y * sv[e2 * 2 + 1];
        }

        // ---- fused mix epilogue (lanes 0-31) ----
        float qsv = sdis[32 + nn] * y2;
        float w1v = fabsf(pa + bw1);
        float c1v = pc + bc1;
        float wwv = fabsf(pw + bww);
        float z = qsv * w1v + c1v;
        float qt = z > 0.f ? z : expm1f(z);
        float val = (half == 0) ? qt * wwv : 0.f;
        val += __shfl_xor(val, 1, 32);
        val += __shfl_xor(val, 2, 32);
        val += __shfl_xor(val, 4, 32);
        val += __shfl_xor(val, 8, 32);
        val += __shfl_xor(val, 16, 32);
        if (l == 0) out[b] = val + p96 + bhc;

        // next iteration needs Hw free: ensure all reads of this batch retired
        WSYNC();

        // rotate prefetched scalars
        pa = pa_n; pc = pc_n; pw = pw_n; p96 = p96_n; q = q_n;
    }
}

// ======================= launch =======================
extern "C" void kernel_launch(void* const* d_in, const int* in_sizes, int n_in,
                              void* d_out, int out_size, void* d_ws, size_t ws_size,
                              hipStream_t stream) {
    const float* agent_qs = (const float*)d_in[0];
    const float* states   = (const float*)d_in[1];
    const float* indiv_us = (const float*)d_in[2];
    const float* edge_W   = (const float*)d_in[3];
    const float* edge_b   = (const float*)d_in[4];
    const float* wline1   = (const float*)d_in[5];
    const float* wline2   = (const float*)d_in[6];
    const float* hw1_w1 = (const float*)d_in[7];
    const float* hw1_b1 = (const float*)d_in[8];
    const float* hw1_w2 = (const float*)d_in[9];
    const float* hw1_b2 = (const float*)d_in[10];
    const float* hc1_w1 = (const float*)d_in[11];
    const float* hc1_b1 = (const float*)d_in[12];
    const float* hc1_w2 = (const float*)d_in[13];
    const float* hc1_b2 = (const float*)d_in[14];
    const float* hw_w1  = (const float*)d_in[15];
    const float* hw_b1  = (const float*)d_in[16];
    const float* hw_w2  = (const float*)d_in[17];
    const float* hw_b2  = (const float*)d_in[18];
    const float* hc_w1  = (const float*)d_in[19];
    const float* hc_b1  = (const float*)d_in[20];
    const float* hc_w2  = (const float*)d_in[21];
    const float* hc_b2  = (const float*)d_in[22];

    char* ws = (char*)d_ws;
    size_t o_states16 = 0;                                   // 33,554,432
    size_t o_W1t  = o_states16 + (size_t)BATCH * SDIM * 2;   // 2,097,152
    size_t o_b1   = o_W1t + (size_t)NH * SDIM * 2;           // 4096
    size_t o_W2t  = o_b1 + 4096;                             // 49,152
    size_t o_hcw2 = o_W2t + 49152;                           // 512
    size_t o_Pp   = o_hcw2 + 512;                            // 16384*104*4 = 6.8MB

    f16*   states16 = (f16*)(ws + o_states16);
    f16*   W1t      = (f16*)(ws + o_W1t);
    float* b1cat    = (float*)(ws + o_b1);
    f16*   W2t      = (f16*)(ws + o_W2t);
    f16*   hcw2     = (f16*)(ws + o_hcw2);
    float* Pp       = (float*)(ws + o_Pp);

    k_front<<<NB_FRONT, 256, 0, stream>>>(
        states,
        hw1_w1, hc1_w1, hw_w1, hc_w1, hw1_b1, hc1_b1, hw_b1, hc_b1,
        hw1_w2, hc1_w2, hw_w2, hc_w2,
        states16, W1t, b1cat, W2t, hcw2);
    k_gemm<<<256, 512, 0, stream>>>(states16, W1t, b1cat, W2t, hcw2, Pp);
    k_hgcn_ep<<<BATCH / 16, 256, 0, stream>>>(
        agent_qs, indiv_us, edge_W, edge_b, wline1, wline2, Pp,
        hw1_b2, hc1_b2, hw_b2, hc_b2, (float*)d_out);
}

// Round 13
// 115.488 us; speedup vs baseline: 1.4215x; 1.1386x over previous
//
#include <hip/hip_runtime.h>
#include <cstdint>

typedef _Float16 f16;
typedef _Float16 f16x2 __attribute__((ext_vector_type(2)));
typedef _Float16 f16x4 __attribute__((ext_vector_type(4)));
typedef _Float16 f16x8 __attribute__((ext_vector_type(8)));
typedef float f32x4 __attribute__((ext_vector_type(4)));

#define AS1U const __attribute__((address_space(1))) unsigned int
#define AS3U __attribute__((address_space(3))) unsigned int

__device__ __forceinline__ void gload_lds16(const void* g, void* l) {
    __builtin_amdgcn_global_load_lds((AS1U*)g, (AS3U*)l, 16, 0, 0);
}

// wave-local LDS sync: HGCN reduction state is per-wave (64 lanes, lockstep)
#define WSYNC() asm volatile("s_waitcnt lgkmcnt(0)" ::: "memory")
#define CFENCE() asm volatile("" ::: "memory")

#define BATCH 16384
#define NAG   32
#define OBS   96
#define SDIM  1024
#define NE    64
#define HIDN  256
#define NH    1024

// k_main grid layout: HGCN first (long pole), then conv + packs co-resident
#define NB_HG 4096
#define NB_ST 1024
#define NB_PW 256
#define NB_SM 101
#define NB_MAIN (NB_HG + NB_ST + NB_PW + NB_SM)

// ======================= K_MAIN: HGCN -> qs_tot  ||  conv + weight packs =======================
__global__ __launch_bounds__(256) void k_main(
    const float* __restrict__ agent_qs, const float* __restrict__ states,
    const float* __restrict__ indiv_us, const float* __restrict__ edge_W,
    const float* __restrict__ edge_b, const float* __restrict__ wline1,
    const float* __restrict__ wline2,
    const float* __restrict__ w1a, const float* __restrict__ w1b,
    const float* __restrict__ w1c, const float* __restrict__ w1d,
    const float* __restrict__ b1a, const float* __restrict__ b1b,
    const float* __restrict__ b1c, const float* __restrict__ b1d,
    const float* __restrict__ w2a, const float* __restrict__ w2b,
    const float* __restrict__ w2c, const float* __restrict__ w2d,
    f16* __restrict__ states16, f16* __restrict__ W1t, float* __restrict__ b1cat,
    f16* __restrict__ W2t, f16* __restrict__ hcw2, float* __restrict__ qs_tot) {
    // arena: eWs 13312 | swa 512 | Hs(f16) 16896 | sv 1024 | stt 512 | sdis 1024 | sbinv 1024 = 34304
    __shared__ __align__(16) char arena[34304];
    const int tid = threadIdx.x;
    int bid = blockIdx.x;

    if (bid < NB_HG) {
        // ---------------- HGCN (R8 body, writes qs_tot; no Pp dependency) ----------------
        f16*   eWs   = (f16*)arena;
        float* swa   = (float*)(arena + 13312);
        f16*   HsB   = (f16*)(arena + 13824);
        float* svB   = (float*)(arena + 30720);
        float* sttB  = (float*)(arena + 31744);
        float* sdisB = (float*)(arena + 32256);
        float* sbinvB= (float*)(arena + 33280);

        const int w = tid >> 6, l = tid & 63;
        const int b = bid * 4 + w;
        f16*   Hw    = HsB + w * (32 * 66);
        float* sv    = svB + w * 64;
        float* stt   = sttB + w * 32;
        float* sdis  = sdisB + w * 64;
        float* sbinv = sbinvB + w * 64;

        const int nn = l & 31, half = l >> 5;
        float q = agent_qs[(size_t)b * 32 + nn];

        for (int i = tid; i < 6144; i += 256) {
            int k = i >> 6, n = i & 63;
            eWs[n * 104 + k] = (f16)edge_W[i];
        }
        if (tid < 64) swa[tid] = fabsf(wline1[tid]);
        else if (tid < 128) swa[tid] = fabsf(wline2[tid - 64]);
        __syncthreads();

        const int lm = l & 15, lk = l >> 4;
        const float* ub = indiv_us + (size_t)b * (NAG * OBS);

        #pragma unroll
        for (int mt = 0; mt < 2; mt++) {
            f16x8 af[3];
            #pragma unroll
            for (int ks = 0; ks < 3; ks++) {
                const float* up = ub + (mt * 16 + lm) * 96 + ks * 32 + lk * 8;
                float4 v0 = *(const float4*)up;
                float4 v1 = *(const float4*)(up + 4);
                af[ks] = (f16x8){ (f16)v0.x, (f16)v0.y, (f16)v0.z, (f16)v0.w,
                                  (f16)v1.x, (f16)v1.y, (f16)v1.z, (f16)v1.w };
            }
            #pragma unroll
            for (int nt = 0; nt < 4; nt++) {
                f32x4 acc = {0.f, 0.f, 0.f, 0.f};
                #pragma unroll
                for (int ks = 0; ks < 3; ks++) {
                    f16x8 bb = *(const f16x8*)&eWs[(nt * 16 + lm) * 104 + ks * 32 + lk * 8];
                    acc = __builtin_amdgcn_mfma_f32_16x16x32_f16(af[ks], bb, acc, 0, 0, 0);
                }
                int col = nt * 16 + lm;
                float bias = edge_b[col];
                #pragma unroll
                for (int r = 0; r < 4; r++) {
                    int row = mt * 16 + lk * 4 + r;
                    float hv = acc[r] + bias;
                    Hw[row * 66 + col] = (f16)(hv > 0.f ? hv : 0.f);
                }
            }
        }
        WSYNC();

        float bsum = 0.f;
        #pragma unroll
        for (int n = 0; n < 32; n++) bsum += (float)Hw[n * 66 + l];
        sbinv[l] = bsum > 0.f ? 1.f / bsum : 0.f;

        float dd = 0.f;
        #pragma unroll 8
        for (int e2 = 0; e2 < 32; e2++) {
            f16x2 h2 = *(const f16x2*)&Hw[nn * 66 + e2 * 2];
            dd += (float)h2.x * swa[half * 64 + e2 * 2] + (float)h2.y * swa[half * 64 + e2 * 2 + 1];
        }
        float dis = dd > 0.f ? rsqrtf(dd) : 0.f;
        sdis[l] = dis;
        if (half == 0) stt[nn] = dis * q;
        WSYNC();

        float s1 = 0.f;
        #pragma unroll
        for (int n = 0; n < 32; n++) s1 += (float)Hw[n * 66 + l] * stt[n];
        sv[l] = s1 * swa[l] * sbinv[l];
        WSYNC();

        float y1 = 0.f;
        #pragma unroll 8
        for (int e2 = 0; e2 < 32; e2++) {
            f16x2 h2 = *(const f16x2*)&Hw[nn * 66 + e2 * 2];
            y1 += (float)h2.x * sv[e2 * 2] + (float)h2.y * sv[e2 * 2 + 1];
        }
        float x2 = sdis[nn] * y1;
        if (half == 0) stt[nn] = sdis[32 + nn] * x2;
        WSYNC();

        float s2 = 0.f;
        #pragma unroll
        for (int n = 0; n < 32; n++) s2 += (float)Hw[n * 66 + l] * stt[n];
        sv[l] = s2 * swa[64 + l] * sbinv[l];
        WSYNC();

        float y2 = 0.f;
        #pragma unroll 8
        for (int e2 = 0; e2 < 32; e2++) {
            f16x2 h2 = *(const f16x2*)&Hw[nn * 66 + e2 * 2];
            y2 += (float)h2.x * sv[e2 * 2] + (float)h2.y * sv[e2 * 2 + 1];
        }
        if (half == 0) qs_tot[(size_t)b * 32 + nn] = sdis[32 + nn] * y2;
        return;
    }
    bid -= NB_HG;

    if (bid < NB_ST) {                    // states fp32 -> fp16 (grid-stride)
        int i = bid * 256 + tid;
        const int n4 = BATCH * SDIM / 4;
        const int stride = NB_ST * 256;
        for (; i < n4; i += stride) {
            float4 v = ((const float4*)states)[i];
            f16x4 h = { (f16)v.x, (f16)v.y, (f16)v.z, (f16)v.w };
            ((f16x4*)states16)[i] = h;
        }
        return;
    }
    bid -= NB_ST;
    if (bid < NB_PW) {                    // W1 pack via LDS transpose
        float* tile = (float*)arena;      // [64][65] = 16640 B
        int mlp = bid >> 6, rem = bid & 63, kt = rem >> 2, ct = rem & 3;
        const float* src = (mlp == 0) ? w1a : (mlp == 1) ? w1b : (mlp == 2) ? w1c : w1d;
        int k0 = kt * 64, c0 = ct * 64;
        for (int i = tid; i < 4096; i += 256) {
            int kk = i >> 6, cc = i & 63;
            tile[kk * 65 + cc] = src[(size_t)(k0 + kk) * 256 + c0 + cc];
        }
        __syncthreads();
        for (int i = tid; i < 4096; i += 256) {
            int cc = i >> 6, kk = i & 63;
            W1t[(size_t)(mlp * 256 + c0 + cc) * 1024 + k0 + kk] = (f16)tile[kk * 65 + cc];
        }
        return;
    }
    bid -= NB_PW;
    {                                     // W2t, hcw2, b1cat
        int i = bid * 256 + tid;
        if (i < 24576) {
            int mp = i >> 13, rem = i & 8191, oo = rem >> 8, kk = rem & 255;
            const float* src = (mp == 0) ? w2a : (mp == 1) ? w2b : w2c;
            W2t[i] = (f16)src[kk * 32 + oo];
        } else if (i < 24832) {
            int k = i - 24576;
            hcw2[k] = (f16)w2d[k];
        } else if (i < 25856) {
            int n = i - 24832;
            int mlp = n >> 8, c = n & 255;
            const float* bsrc = (mlp == 0) ? b1a : (mlp == 1) ? b1b : (mlp == 2) ? b1c : b1d;
            b1cat[n] = bsrc[c];
        }
    }
}

// ======================= K_GEMM: 256x256, 4-quadrant phase interleave (R8, unchanged) =======================
__global__ __launch_bounds__(512) void k_gemm(
    const f16* __restrict__ A, const f16* __restrict__ B,
    const float* __restrict__ b1cat, const f16* __restrict__ W2t,
    const f16* __restrict__ hcw2, float* __restrict__ Pp) {
    __shared__ __align__(16) char smem[131072];
    f16* Asb = (f16*)smem;
    f16* Bsb = (f16*)(smem + 65536);
    f16* Ts  = (f16*)smem;

    const int tid = threadIdx.x;
    const int w = tid >> 6, l = tid & 63;
    const int lm = l & 15, lk = l >> 4;
    const int wm = w >> 2, wn = w & 3;
    const int p = blockIdx.x;
    const int xcd = p & 7, s = p >> 3;
    const int mt = xcd * 8 + (s >> 2);
    const int nt = s & 3;
    const int m0 = mt * 256, n0 = nt * 256;
    const int c0 = w * 4;
    const int srow = l >> 3;
    const int gchunk = (l & 7) ^ srow;

    float bj[4];
    #pragma unroll
    for (int j = 0; j < 4; j++) bj[j] = b1cat[n0 + wn * 64 + j * 16 + lm];

    f32x4 acc[8][4];
    #pragma unroll
    for (int i = 0; i < 8; i++)
        #pragma unroll
        for (int j = 0; j < 4; j++) acc[i][j] = (f32x4){0.f, 0.f, 0.f, 0.f};

#define STAGE(KT, BI)                                                                     \
    {                                                                                     \
        f16* Ad = Asb + (BI) * 16384;                                                     \
        f16* Bd = Bsb + (BI) * 16384;                                                     \
        _Pragma("unroll")                                                                 \
        for (int i_ = 0; i_ < 4; i_++) {                                                  \
            int cc = c0 + i_;                                                             \
            gload_lds16(&A[(size_t)(m0 + cc * 8 + srow) * 1024 + (KT) * 64 + gchunk * 8], \
                        &Ad[cc * 512]);                                                   \
            gload_lds16(&B[(size_t)(n0 + cc * 8 + srow) * 1024 + (KT) * 64 + gchunk * 8], \
                        &Bd[cc * 512]);                                                   \
        }                                                                                 \
    }

    STAGE(0, 0);
    STAGE(1, 1);

    for (int kt = 0; kt < 16; kt++) {
        if (kt < 15) { asm volatile("s_waitcnt vmcnt(8)" ::: "memory"); }
        else         { asm volatile("s_waitcnt vmcnt(0)" ::: "memory"); }
        CFENCE(); __builtin_amdgcn_s_barrier(); CFENCE();

        const f16* As_ = Asb + (kt & 1) * 16384;
        const f16* Bs_ = Bsb + (kt & 1) * 16384;
        const int swlo = ((lk ^ (lm & 7)) << 3);
        const int swhi = (((4 + lk) ^ (lm & 7)) << 3);

        f16x8 af[4][2], bf01[2][2], bf23[2][2];

        // ---- phase A ----
        #pragma unroll
        for (int i = 0; i < 4; i++) {
            af[i][0] = *(const f16x8*)&As_[(wm * 128 + i * 16 + lm) * 64 + swlo];
            af[i][1] = *(const f16x8*)&As_[(wm * 128 + i * 16 + lm) * 64 + swhi];
        }
        #pragma unroll
        for (int j = 0; j < 2; j++) {
            bf01[j][0] = *(const f16x8*)&Bs_[(wn * 64 + j * 16 + lm) * 64 + swlo];
            bf01[j][1] = *(const f16x8*)&Bs_[(wn * 64 + j * 16 + lm) * 64 + swhi];
        }
        __builtin_amdgcn_s_setprio(1);
        #pragma unroll
        for (int ks = 0; ks < 2; ks++)
            #pragma unroll
            for (int i = 0; i < 4; i++)
                #pragma unroll
                for (int j = 0; j < 2; j++)
                    acc[i][j] = __builtin_amdgcn_mfma_f32_16x16x32_f16(af[i][ks], bf01[j][ks], acc[i][j], 0, 0, 0);
        __builtin_amdgcn_s_setprio(0);
        CFENCE(); __builtin_amdgcn_s_barrier(); CFENCE();

        // ---- phase B ----
        #pragma unroll
        for (int j = 0; j < 2; j++) {
            bf23[j][0] = *(const f16x8*)&Bs_[(wn * 64 + (2 + j) * 16 + lm) * 64 + swlo];
            bf23[j][1] = *(const f16x8*)&Bs_[(wn * 64 + (2 + j) * 16 + lm) * 64 + swhi];
        }
        __builtin_amdgcn_s_setprio(1);
        #pragma unroll
        for (int ks = 0; ks < 2; ks++)
            #pragma unroll
            for (int i = 0; i < 4; i++)
                #pragma unroll
                for (int j = 0; j < 2; j++)
                    acc[i][2 + j] = __builtin_amdgcn_mfma_f32_16x16x32_f16(af[i][ks], bf23[j][ks], acc[i][2 + j], 0, 0, 0);
        __builtin_amdgcn_s_setprio(0);
        CFENCE(); __builtin_amdgcn_s_barrier(); CFENCE();

        // ---- phase C ----
        #pragma unroll
        for (int i = 0; i < 4; i++) {
            af[i][0] = *(const f16x8*)&As_[(wm * 128 + (4 + i) * 16 + lm) * 64 + swlo];
            af[i][1] = *(const f16x8*)&As_[(wm * 128 + (4 + i) * 16 + lm) * 64 + swhi];
        }
        __builtin_amdgcn_s_setprio(1);
        #pragma unroll
        for (int ks = 0; ks < 2; ks++)
            #pragma unroll
            for (int i = 0; i < 4; i++)
                #pragma unroll
                for (int j = 0; j < 2; j++)
                    acc[4 + i][j] = __builtin_amdgcn_mfma_f32_16x16x32_f16(af[i][ks], bf01[j][ks], acc[4 + i][j], 0, 0, 0);
        __builtin_amdgcn_s_setprio(0);
        CFENCE(); __builtin_amdgcn_s_barrier(); CFENCE();

        // ---- phase D ----
        if (kt < 14) STAGE(kt + 2, kt & 1);
        __builtin_amdgcn_s_setprio(1);
        #pragma unroll
        for (int ks = 0; ks < 2; ks++)
            #pragma unroll
            for (int i = 0; i < 4; i++)
                #pragma unroll
                for (int j = 0; j < 2; j++)
                    acc[4 + i][2 + j] = __builtin_amdgcn_mfma_f32_16x16x32_f16(af[i][ks], bf23[j][ks], acc[4 + i][2 + j], 0, 0, 0);
        __builtin_amdgcn_s_setprio(0);
    }
#undef STAGE

    __syncthreads();

    const int mlp = nt;
    #pragma unroll
    for (int pass = 0; pass < 2; pass++) {
        if (wm == pass) {
            #pragma unroll
            for (int i = 0; i < 8; i++)
                #pragma unroll
                for (int r = 0; r < 4; r++) {
                    int rl = i * 16 + lk * 4 + r;
                    #pragma unroll
                    for (int j = 0; j < 4; j++) {
                        float v = acc[i][j][r] + bj[j];
                        Ts[rl * 264 + wn * 64 + j * 16 + lm] = (f16)(v > 0.f ? v : 0.f);
                    }
                }
        }
        __syncthreads();
        const int grow = m0 + pass * 128 + w * 16;
        if (mlp < 3) {
            const f16* wb = W2t + mlp * 8192;
            f32x4 acc2[2];
            acc2[0] = (f32x4){0, 0, 0, 0}; acc2[1] = (f32x4){0, 0, 0, 0};
            #pragma unroll
            for (int ks = 0; ks < 8; ks++) {
                f16x8 a  = *(const f16x8*)&Ts[(w * 16 + lm) * 264 + ks * 32 + lk * 8];
                f16x8 b0 = *(const f16x8*)&wb[lm * 256 + ks * 32 + lk * 8];
                f16x8 b1 = *(const f16x8*)&wb[(16 + lm) * 256 + ks * 32 + lk * 8];
                acc2[0] = __builtin_amdgcn_mfma_f32_16x16x32_f16(a, b0, acc2[0], 0, 0, 0);
                acc2[1] = __builtin_amdgcn_mfma_f32_16x16x32_f16(a, b1, acc2[1], 0, 0, 0);
            }
            #pragma unroll
            for (int j2 = 0; j2 < 2; j2++)
                #pragma unroll
                for (int r = 0; r < 4; r++)
                    Pp[(size_t)(grow + lk * 4 + r) * 104 + mlp * 32 + j2 * 16 + lm] = acc2[j2][r];
        } else {
            f32x4 acc2 = (f32x4){0, 0, 0, 0};
            #pragma unroll
            for (int ks = 0; ks < 8; ks++) {
                f16x8 a = *(const f16x8*)&Ts[(w * 16 + lm) * 264 + ks * 32 + lk * 8];
                f16x8 bz = (f16x8){0, 0, 0, 0, 0, 0, 0, 0};
                if (lm == 0) bz = *(const f16x8*)&hcw2[ks * 32 + lk * 8];
                acc2 = __builtin_amdgcn_mfma_f32_16x16x32_f16(a, bz, acc2, 0, 0, 0);
            }
            if (lm == 0)
                #pragma unroll
                for (int r = 0; r < 4; r++)
                    Pp[(size_t)(grow + lk * 4 + r) * 104 + 96] = acc2[r];
        }
        if (pass == 0) __syncthreads();
    }
}

// ======================= K_EP: mix epilogue (single-Pp) =======================
__global__ __launch_bounds__(256) void k_ep(
    const float* __restrict__ Pp, const float* __restrict__ qs_tot,
    const float* __restrict__ hw1_b2, const float* __restrict__ hc1_b2,
    const float* __restrict__ hw_b2, const float* __restrict__ hc_b2,
    float* __restrict__ out) {
    const int tid = threadIdx.x;
    const int row = blockIdx.x * 32 + (tid >> 3);
    const int q8 = tid & 7, o = q8 * 4;
    const float* p0 = Pp + (size_t)row * 104;
    f32x4 a0 = *(const f32x4*)(p0 + o);
    f32x4 c0 = *(const f32x4*)(p0 + 32 + o);
    f32x4 w0 = *(const f32x4*)(p0 + 64 + o);
    f32x4 qs = *(const f32x4*)(qs_tot + (size_t)row * 32 + o);
    float val = 0.f;
    #pragma unroll
    for (int j = 0; j < 4; j++) {
        float wv1 = fabsf(a0[j] + hw1_b2[o + j]);
        float cv1 = c0[j] + hc1_b2[o + j];
        float wv  = fabsf(w0[j] + hw_b2[o + j]);
        float z = qs[j] * wv1 + cv1;
        float qt = z > 0.f ? z : expm1f(z);
        val += qt * wv;
    }
    val += __shfl_xor(val, 1);
    val += __shfl_xor(val, 2);
    val += __shfl_xor(val, 4);
    if (q8 == 0) out[row] = val + p0[96] + hc_b2[0];
}

// ======================= launch =======================
extern "C" void kernel_launch(void* const* d_in, const int* in_sizes, int n_in,
                              void* d_out, int out_size, void* d_ws, size_t ws_size,
                              hipStream_t stream) {
    const float* agent_qs = (const float*)d_in[0];
    const float* states   = (const float*)d_in[1];
    const float* indiv_us = (const float*)d_in[2];
    const float* edge_W   = (const float*)d_in[3];
    const float* edge_b   = (const float*)d_in[4];
    const float* wline1   = (const float*)d_in[5];
    const float* wline2   = (const float*)d_in[6];
    const float* hw1_w1 = (const float*)d_in[7];
    const float* hw1_b1 = (const float*)d_in[8];
    const float* hw1_w2 = (const float*)d_in[9];
    const float* hw1_b2 = (const float*)d_in[10];
    const float* hc1_w1 = (const float*)d_in[11];
    const float* hc1_b1 = (const float*)d_in[12];
    const float* hc1_w2 = (const float*)d_in[13];
    const float* hc1_b2 = (const float*)d_in[14];
    const float* hw_w1  = (const float*)d_in[15];
    const float* hw_b1  = (const float*)d_in[16];
    const float* hw_w2  = (const float*)d_in[17];
    const float* hw_b2  = (const float*)d_in[18];
    const float* hc_w1  = (const float*)d_in[19];
    const float* hc_b1  = (const float*)d_in[20];
    const float* hc_w2  = (const float*)d_in[21];
    const float* hc_b2  = (const float*)d_in[22];

    char* ws = (char*)d_ws;
    size_t o_states16 = 0;                                   // 33,554,432
    size_t o_W1t  = o_states16 + (size_t)BATCH * SDIM * 2;   // 2,097,152
    size_t o_b1   = o_W1t + (size_t)NH * SDIM * 2;           // 4096
    size_t o_W2t  = o_b1 + 4096;                             // 49,152
    size_t o_hcw2 = o_W2t + 49152;                           // 512
    size_t o_Pp   = o_hcw2 + 512;                            // 16384*104*4 = 6.8MB
    size_t o_qs   = o_Pp + (size_t)BATCH * 104 * 4;          // 2MB

    f16*   states16 = (f16*)(ws + o_states16);
    f16*   W1t      = (f16*)(ws + o_W1t);
    float* b1cat    = (float*)(ws + o_b1);
    f16*   W2t      = (f16*)(ws + o_W2t);
    f16*   hcw2     = (f16*)(ws + o_hcw2);
    float* Pp       = (float*)(ws + o_Pp);
    float* qs_tot   = (float*)(ws + o_qs);

    k_main<<<NB_MAIN, 256, 0, stream>>>(
        agent_qs, states, indiv_us, edge_W, edge_b, wline1, wline2,
        hw1_w1, hc1_w1, hw_w1, hc_w1, hw1_b1, hc1_b1, hw_b1, hc_b1,
        hw1_w2, hc1_w2, hw_w2, hc_w2,
        states16, W1t, b1cat, W2t, hcw2, qs_tot);
    k_gemm<<<256, 512, 0, stream>>>(states16, W1t, b1cat, W2t, hcw2, Pp);
    k_ep<<<BATCH / 32, 256, 0, stream>>>(Pp, qs_tot, hw1_b2, hc1_b2, hw_b2, hc_b2,
                                         (float*)d_out);
}

// Round 14
// 115.282 us; speedup vs baseline: 1.4240x; 1.0018x over previous
//
#include <hip/hip_runtime.h>
#include <cstdint>

typedef _Float16 f16;
typedef _Float16 f16x2 __attribute__((ext_vector_type(2)));
typedef _Float16 f16x4 __attribute__((ext_vector_type(4)));
typedef _Float16 f16x8 __attribute__((ext_vector_type(8)));
typedef float f32x4 __attribute__((ext_vector_type(4)));

#define AS1U const __attribute__((address_space(1))) unsigned int
#define AS3U __attribute__((address_space(3))) unsigned int

__device__ __forceinline__ void gload_lds16(const void* g, void* l) {
    __builtin_amdgcn_global_load_lds((AS1U*)g, (AS3U*)l, 16, 0, 0);
}

// wave-local LDS sync: HGCN reduction state is per-wave (64 lanes, lockstep)
#define WSYNC() asm volatile("s_waitcnt lgkmcnt(0)" ::: "memory")
#define CFENCE() asm volatile("" ::: "memory")

#define BATCH 16384
#define NAG   32
#define OBS   96
#define SDIM  1024
#define NE    64
#define HIDN  256
#define NH    1024

// k_main grid: first 5120 blocks interleave HGCN(4)/conv(1) per group of 5; then packs
#define NB_MIX 5120
#define NB_PW  256
#define NB_SM  101
#define NB_MAIN (NB_MIX + NB_PW + NB_SM)

// ======================= K_MAIN: HGCN || conv interleaved + weight packs =======================
__global__ __launch_bounds__(256, 5) void k_main(
    const float* __restrict__ agent_qs, const float* __restrict__ states,
    const float* __restrict__ indiv_us, const float* __restrict__ edge_W,
    const float* __restrict__ edge_b, const float* __restrict__ wline1,
    const float* __restrict__ wline2,
    const float* __restrict__ w1a, const float* __restrict__ w1b,
    const float* __restrict__ w1c, const float* __restrict__ w1d,
    const float* __restrict__ b1a, const float* __restrict__ b1b,
    const float* __restrict__ b1c, const float* __restrict__ b1d,
    const float* __restrict__ w2a, const float* __restrict__ w2b,
    const float* __restrict__ w2c, const float* __restrict__ w2d,
    f16* __restrict__ states16, f16* __restrict__ W1t, float* __restrict__ b1cat,
    f16* __restrict__ W2t, f16* __restrict__ hcw2, float* __restrict__ qs_tot) {
    // arena: eWs 13312 | swa 512 | Hs(f16) 16896 | sv 1024 | stt 512 = 32256 (5 blocks/CU)
    __shared__ __align__(16) char arena[32256];
    const int tid = threadIdx.x;
    int bid = blockIdx.x;

    if (bid < NB_MIX) {
        const int g = bid / 5, r = bid - g * 5;
        if (r == 4) {                     // conv block (1 of 5), grid-stride over states
            int i = g * 256 + tid;
            const int n4 = BATCH * SDIM / 4;
            const int stride = 1024 * 256;
            for (; i < n4; i += stride) {
                float4 v = ((const float4*)states)[i];
                f16x4 h = { (f16)v.x, (f16)v.y, (f16)v.z, (f16)v.w };
                ((f16x4*)states16)[i] = h;
            }
            return;
        }
        // ---------------- HGCN (R8 body; sdis/sbinv in registers, R10-verified) ----------------
        const int hbid = g * 4 + r;       // 0..4095
        f16*   eWs  = (f16*)arena;
        float* swa  = (float*)(arena + 13312);
        f16*   HsB  = (f16*)(arena + 13824);
        float* svB  = (float*)(arena + 30720);
        float* sttB = (float*)(arena + 31744);

        const int w = tid >> 6, l = tid & 63;
        const int b = hbid * 4 + w;
        f16*   Hw  = HsB + w * (32 * 66);
        float* sv  = svB + w * 64;
        float* stt = sttB + w * 32;

        const int nn = l & 31, half = l >> 5;
        float q = agent_qs[(size_t)b * 32 + nn];

        for (int i = tid; i < 6144; i += 256) {
            int k = i >> 6, n = i & 63;
            eWs[n * 104 + k] = (f16)edge_W[i];
        }
        if (tid < 64) swa[tid] = fabsf(wline1[tid]);
        else if (tid < 128) swa[tid] = fabsf(wline2[tid - 64]);
        __syncthreads();

        const float swal1 = swa[l];
        const float swal2 = swa[64 + l];

        const int lm = l & 15, lk = l >> 4;
        const float* ub = indiv_us + (size_t)b * (NAG * OBS);

        #pragma unroll
        for (int mt = 0; mt < 2; mt++) {
            f16x8 af[3];
            #pragma unroll
            for (int ks = 0; ks < 3; ks++) {
                const float* up = ub + (mt * 16 + lm) * 96 + ks * 32 + lk * 8;
                float4 v0 = *(const float4*)up;
                float4 v1 = *(const float4*)(up + 4);
                af[ks] = (f16x8){ (f16)v0.x, (f16)v0.y, (f16)v0.z, (f16)v0.w,
                                  (f16)v1.x, (f16)v1.y, (f16)v1.z, (f16)v1.w };
            }
            #pragma unroll
            for (int nt = 0; nt < 4; nt++) {
                f32x4 acc = {0.f, 0.f, 0.f, 0.f};
                #pragma unroll
                for (int ks = 0; ks < 3; ks++) {
                    f16x8 bb = *(const f16x8*)&eWs[(nt * 16 + lm) * 104 + ks * 32 + lk * 8];
                    acc = __builtin_amdgcn_mfma_f32_16x16x32_f16(af[ks], bb, acc, 0, 0, 0);
                }
                int col = nt * 16 + lm;
                float bias = edge_b[col];
                #pragma unroll
                for (int r2 = 0; r2 < 4; r2++) {
                    int row = mt * 16 + lk * 4 + r2;
                    float hv = acc[r2] + bias;
                    Hw[row * 66 + col] = (f16)(hv > 0.f ? hv : 0.f);
                }
            }
        }
        WSYNC();

        float bsum = 0.f;
        #pragma unroll
        for (int n = 0; n < 32; n++) bsum += (float)Hw[n * 66 + l];
        const float sbinv_r = bsum > 0.f ? 1.f / bsum : 0.f;

        float dd = 0.f;
        #pragma unroll 8
        for (int e2 = 0; e2 < 32; e2++) {
            f16x2 h2 = *(const f16x2*)&Hw[nn * 66 + e2 * 2];
            dd += (float)h2.x * swa[half * 64 + e2 * 2] + (float)h2.y * swa[half * 64 + e2 * 2 + 1];
        }
        float dis = dd > 0.f ? rsqrtf(dd) : 0.f;
        const float dis_o = __shfl_xor(dis, 32);
        const float dis1 = (half == 0) ? dis : dis_o;   // layer-1 dis of agent nn
        const float dis2 = (half == 0) ? dis_o : dis;   // layer-2 dis of agent nn
        if (half == 0) stt[nn] = dis * q;
        WSYNC();

        float s1 = 0.f;
        #pragma unroll
        for (int n = 0; n < 32; n++) s1 += (float)Hw[n * 66 + l] * stt[n];
        sv[l] = s1 * swal1 * sbinv_r;
        WSYNC();

        float y1 = 0.f;
        #pragma unroll 8
        for (int e2 = 0; e2 < 32; e2++) {
            f16x2 h2 = *(const f16x2*)&Hw[nn * 66 + e2 * 2];
            y1 += (float)h2.x * sv[e2 * 2] + (float)h2.y * sv[e2 * 2 + 1];
        }
        float x2 = dis1 * y1;
        if (half == 0) stt[nn] = dis2 * x2;
        WSYNC();

        float s2 = 0.f;
        #pragma unroll
        for (int n = 0; n < 32; n++) s2 += (float)Hw[n * 66 + l] * stt[n];
        sv[l] = s2 * swal2 * sbinv_r;
        WSYNC();

        float y2 = 0.f;
        #pragma unroll 8
        for (int e2 = 0; e2 < 32; e2++) {
            f16x2 h2 = *(const f16x2*)&Hw[nn * 66 + e2 * 2];
            y2 += (float)h2.x * sv[e2 * 2] + (float)h2.y * sv[e2 * 2 + 1];
        }
        if (half == 0) qs_tot[(size_t)b * 32 + nn] = dis2 * y2;
        return;
    }
    bid -= NB_MIX;

    if (bid < NB_PW) {                    // W1 pack via LDS transpose
        float* tile = (float*)arena;      // [64][65] = 16640 B
        int mlp = bid >> 6, rem = bid & 63, kt = rem >> 2, ct = rem & 3;
        const float* src = (mlp == 0) ? w1a : (mlp == 1) ? w1b : (mlp == 2) ? w1c : w1d;
        int k0 = kt * 64, c0 = ct * 64;
        for (int i = tid; i < 4096; i += 256) {
            int kk = i >> 6, cc = i & 63;
            tile[kk * 65 + cc] = src[(size_t)(k0 + kk) * 256 + c0 + cc];
        }
        __syncthreads();
        for (int i = tid; i < 4096; i += 256) {
            int cc = i >> 6, kk = i & 63;
            W1t[(size_t)(mlp * 256 + c0 + cc) * 1024 + k0 + kk] = (f16)tile[kk * 65 + cc];
        }
        return;
    }
    bid -= NB_PW;
    {                                     // W2t, hcw2, b1cat
        int i = bid * 256 + tid;
        if (i < 24576) {
            int mp = i >> 13, rem = i & 8191, oo = rem >> 8, kk = rem & 255;
            const float* src = (mp == 0) ? w2a : (mp == 1) ? w2b : w2c;
            W2t[i] = (f16)src[kk * 32 + oo];
        } else if (i < 24832) {
            int k = i - 24576;
            hcw2[k] = (f16)w2d[k];
        } else if (i < 25856) {
            int n = i - 24832;
            int mlp = n >> 8, c = n & 255;
            const float* bsrc = (mlp == 0) ? b1a : (mlp == 1) ? b1b : (mlp == 2) ? b1c : b1d;
            b1cat[n] = bsrc[c];
        }
    }
}

// ======================= K_GEMM: 256x256, 4-quadrant phase interleave (R8, unchanged) =======================
__global__ __launch_bounds__(512) void k_gemm(
    const f16* __restrict__ A, const f16* __restrict__ B,
    const float* __restrict__ b1cat, const f16* __restrict__ W2t,
    const f16* __restrict__ hcw2, float* __restrict__ Pp) {
    __shared__ __align__(16) char smem[131072];
    f16* Asb = (f16*)smem;
    f16* Bsb = (f16*)(smem + 65536);
    f16* Ts  = (f16*)smem;

    const int tid = threadIdx.x;
    const int w = tid >> 6, l = tid & 63;
    const int lm = l & 15, lk = l >> 4;
    const int wm = w >> 2, wn = w & 3;
    const int p = blockIdx.x;
    const int xcd = p & 7, s = p >> 3;
    const int mt = xcd * 8 + (s >> 2);
    const int nt = s & 3;
    const int m0 = mt * 256, n0 = nt * 256;
    const int c0 = w * 4;
    const int srow = l >> 3;
    const int gchunk = (l & 7) ^ srow;

    float bj[4];
    #pragma unroll
    for (int j = 0; j < 4; j++) bj[j] = b1cat[n0 + wn * 64 + j * 16 + lm];

    f32x4 acc[8][4];
    #pragma unroll
    for (int i = 0; i < 8; i++)
        #pragma unroll
        for (int j = 0; j < 4; j++) acc[i][j] = (f32x4){0.f, 0.f, 0.f, 0.f};

#define STAGE(KT, BI)                                                                     \
    {                                                                                     \
        f16* Ad = Asb + (BI) * 16384;                                                     \
        f16* Bd = Bsb + (BI) * 16384;                                                     \
        _Pragma("unroll")                                                                 \
        for (int i_ = 0; i_ < 4; i_++) {                                                  \
            int cc = c0 + i_;                                                             \
            gload_lds16(&A[(size_t)(m0 + cc * 8 + srow) * 1024 + (KT) * 64 + gchunk * 8], \
                        &Ad[cc * 512]);                                                   \
            gload_lds16(&B[(size_t)(n0 + cc * 8 + srow) * 1024 + (KT) * 64 + gchunk * 8], \
                        &Bd[cc * 512]);                                                   \
        }                                                                                 \
    }

    STAGE(0, 0);
    STAGE(1, 1);

    for (int kt = 0; kt < 16; kt++) {
        if (kt < 15) { asm volatile("s_waitcnt vmcnt(8)" ::: "memory"); }
        else         { asm volatile("s_waitcnt vmcnt(0)" ::: "memory"); }
        CFENCE(); __builtin_amdgcn_s_barrier(); CFENCE();

        const f16* As_ = Asb + (kt & 1) * 16384;
        const f16* Bs_ = Bsb + (kt & 1) * 16384;
        const int swlo = ((lk ^ (lm & 7)) << 3);
        const int swhi = (((4 + lk) ^ (lm & 7)) << 3);

        f16x8 af[4][2], bf01[2][2], bf23[2][2];

        // ---- phase A ----
        #pragma unroll
        for (int i = 0; i < 4; i++) {
            af[i][0] = *(const f16x8*)&As_[(wm * 128 + i * 16 + lm) * 64 + swlo];
            af[i][1] = *(const f16x8*)&As_[(wm * 128 + i * 16 + lm) * 64 + swhi];
        }
        #pragma unroll
        for (int j = 0; j < 2; j++) {
            bf01[j][0] = *(const f16x8*)&Bs_[(wn * 64 + j * 16 + lm) * 64 + swlo];
            bf01[j][1] = *(const f16x8*)&Bs_[(wn * 64 + j * 16 + lm) * 64 + swhi];
        }
        __builtin_amdgcn_s_setprio(1);
        #pragma unroll
        for (int ks = 0; ks < 2; ks++)
            #pragma unroll
            for (int i = 0; i < 4; i++)
                #pragma unroll
                for (int j = 0; j < 2; j++)
                    acc[i][j] = __builtin_amdgcn_mfma_f32_16x16x32_f16(af[i][ks], bf01[j][ks], acc[i][j], 0, 0, 0);
        __builtin_amdgcn_s_setprio(0);
        CFENCE(); __builtin_amdgcn_s_barrier(); CFENCE();

        // ---- phase B ----
        #pragma unroll
        for (int j = 0; j < 2; j++) {
            bf23[j][0] = *(const f16x8*)&Bs_[(wn * 64 + (2 + j) * 16 + lm) * 64 + swlo];
            bf23[j][1] = *(const f16x8*)&Bs_[(wn * 64 + (2 + j) * 16 + lm) * 64 + swhi];
        }
        __builtin_amdgcn_s_setprio(1);
        #pragma unroll
        for (int ks = 0; ks < 2; ks++)
            #pragma unroll
            for (int i = 0; i < 4; i++)
                #pragma unroll
                for (int j = 0; j < 2; j++)
                    acc[i][2 + j] = __builtin_amdgcn_mfma_f32_16x16x32_f16(af[i][ks], bf23[j][ks], acc[i][2 + j], 0, 0, 0);
        __builtin_amdgcn_s_setprio(0);
        CFENCE(); __builtin_amdgcn_s_barrier(); CFENCE();

        // ---- phase C ----
        #pragma unroll
        for (int i = 0; i < 4; i++) {
            af[i][0] = *(const f16x8*)&As_[(wm * 128 + (4 + i) * 16 + lm) * 64 + swlo];
            af[i][1] = *(const f16x8*)&As_[(wm * 128 + (4 + i) * 16 + lm) * 64 + swhi];
        }
        __builtin_amdgcn_s_setprio(1);
        #pragma unroll
        for (int ks = 0; ks < 2; ks++)
            #pragma unroll
            for (int i = 0; i < 4; i++)
                #pragma unroll
                for (int j = 0; j < 2; j++)
                    acc[4 + i][j] = __builtin_amdgcn_mfma_f32_16x16x32_f16(af[i][ks], bf01[j][ks], acc[4 + i][j], 0, 0, 0);
        __builtin_amdgcn_s_setprio(0);
        CFENCE(); __builtin_amdgcn_s_barrier(); CFENCE();

        // ---- phase D ----
        if (kt < 14) STAGE(kt + 2, kt & 1);
        __builtin_amdgcn_s_setprio(1);
        #pragma unroll
        for (int ks = 0; ks < 2; ks++)
            #pragma unroll
            for (int i = 0; i < 4; i++)
                #pragma unroll
                for (int j = 0; j < 2; j++)
                    acc[4 + i][2 + j] = __builtin_amdgcn_mfma_f32_16x16x32_f16(af[i][ks], bf23[j][ks], acc[4 + i][2 + j], 0, 0, 0);
        __builtin_amdgcn_s_setprio(0);
    }
#undef STAGE

    __syncthreads();

    const int mlp = nt;
    #pragma unroll
    for (int pass = 0; pass < 2; pass++) {
        if (wm == pass) {
            #pragma unroll
            for (int i = 0; i < 8; i++)
                #pragma unroll
                for (int r = 0; r < 4; r++) {
                    int rl = i * 16 + lk * 4 + r;
                    #pragma unroll
                    for (int j = 0; j < 4; j++) {
                        float v = acc[i][j][r] + bj[j];
                        Ts[rl * 264 + wn * 64 + j * 16 + lm] = (f16)(v > 0.f ? v : 0.f);
                    }
                }
        }
        __syncthreads();
        const int grow = m0 + pass * 128 + w * 16;
        if (mlp < 3) {
            const f16* wb = W2t + mlp * 8192;
            f32x4 acc2[2];
            acc2[0] = (f32x4){0, 0, 0, 0}; acc2[1] = (f32x4){0, 0, 0, 0};
            #pragma unroll
            for (int ks = 0; ks < 8; ks++) {
                f16x8 a  = *(const f16x8*)&Ts[(w * 16 + lm) * 264 + ks * 32 + lk * 8];
                f16x8 b0 = *(const f16x8*)&wb[lm * 256 + ks * 32 + lk * 8];
                f16x8 b1 = *(const f16x8*)&wb[(16 + lm) * 256 + ks * 32 + lk * 8];
                acc2[0] = __builtin_amdgcn_mfma_f32_16x16x32_f16(a, b0, acc2[0], 0, 0, 0);
                acc2[1] = __builtin_amdgcn_mfma_f32_16x16x32_f16(a, b1, acc2[1], 0, 0, 0);
            }
            #pragma unroll
            for (int j2 = 0; j2 < 2; j2++)
                #pragma unroll
                for (int r = 0; r < 4; r++)
                    Pp[(size_t)(grow + lk * 4 + r) * 104 + mlp * 32 + j2 * 16 + lm] = acc2[j2][r];
        } else {
            f32x4 acc2 = (f32x4){0, 0, 0, 0};
            #pragma unroll
            for (int ks = 0; ks < 8; ks++) {
                f16x8 a = *(const f16x8*)&Ts[(w * 16 + lm) * 264 + ks * 32 + lk * 8];
                f16x8 bz = (f16x8){0, 0, 0, 0, 0, 0, 0, 0};
                if (lm == 0) bz = *(const f16x8*)&hcw2[ks * 32 + lk * 8];
                acc2 = __builtin_amdgcn_mfma_f32_16x16x32_f16(a, bz, acc2, 0, 0, 0);
            }
            if (lm == 0)
                #pragma unroll
                for (int r = 0; r < 4; r++)
                    Pp[(size_t)(grow + lk * 4 + r) * 104 + 96] = acc2[r];
        }
        if (pass == 0) __syncthreads();
    }
}

// ======================= K_EP: mix epilogue (single-Pp) =======================
__global__ __launch_bounds__(256) void k_ep(
    const float* __restrict__ Pp, const float* __restrict__ qs_tot,
    const float* __restrict__ hw1_b2, const float* __restrict__ hc1_b2,
    const float* __restrict__ hw_b2, const float* __restrict__ hc_b2,
    float* __restrict__ out) {
    const int tid = threadIdx.x;
    const int row = blockIdx.x * 32 + (tid >> 3);
    const int q8 = tid & 7, o = q8 * 4;
    const float* p0 = Pp + (size_t)row * 104;
    f32x4 a0 = *(const f32x4*)(p0 + o);
    f32x4 c0 = *(const f32x4*)(p0 + 32 + o);
    f32x4 w0 = *(const f32x4*)(p0 + 64 + o);
    f32x4 qs = *(const f32x4*)(qs_tot + (size_t)row * 32 + o);
    float val = 0.f;
    #pragma unroll
    for (int j = 0; j < 4; j++) {
        float wv1 = fabsf(a0[j] + hw1_b2[o + j]);
        float cv1 = c0[j] + hc1_b2[o + j];
        float wv  = fabsf(w0[j] + hw_b2[o + j]);
        float z = qs[j] * wv1 + cv1;
        float qt = z > 0.f ? z : expm1f(z);
        val += qt * wv;
    }
    val += __shfl_xor(val, 1);
    val += __shfl_xor(val, 2);
    val += __shfl_xor(val, 4);
    if (q8 == 0) out[row] = val + p0[96] + hc_b2[0];
}

// ======================= launch =======================
extern "C" void kernel_launch(void* const* d_in, const int* in_sizes, int n_in,
                              void* d_out, int out_size, void* d_ws, size_t ws_size,
                              hipStream_t stream) {
    const float* agent_qs = (const float*)d_in[0];
    const float* states   = (const float*)d_in[1];
    const float* indiv_us = (const float*)d_in[2];
    const float* edge_W   = (const float*)d_in[3];
    const float* edge_b   = (const float*)d_in[4];
    const float* wline1   = (const float*)d_in[5];
    const float* wline2   = (const float*)d_in[6];
    const float* hw1_w1 = (const float*)d_in[7];
    const float* hw1_b1 = (const float*)d_in[8];
    const float* hw1_w2 = (const float*)d_in[9];
    const float* hw1_b2 = (const float*)d_in[10];
    const float* hc1_w1 = (const float*)d_in[11];
    const float* hc1_b1 = (const float*)d_in[12];
    const float* hc1_w2 = (const float*)d_in[13];
    const float* hc1_b2 = (const float*)d_in[14];
    const float* hw_w1  = (const float*)d_in[15];
    const float* hw_b1  = (const float*)d_in[16];
    const float* hw_w2  = (const float*)d_in[17];
    const float* hw_b2  = (const float*)d_in[18];
    const float* hc_w1  = (const float*)d_in[19];
    const float* hc_b1  = (const float*)d_in[20];
    const float* hc_w2  = (const float*)d_in[21];
    const float* hc_b2  = (const float*)d_in[22];

    char* ws = (char*)d_ws;
    size_t o_states16 = 0;                                   // 33,554,432
    size_t o_W1t  = o_states16 + (size_t)BATCH * SDIM * 2;   // 2,097,152
    size_t o_b1   = o_W1t + (size_t)NH * SDIM * 2;           // 4096
    size_t o_W2t  = o_b1 + 4096;                             // 49,152
    size_t o_hcw2 = o_W2t + 49152;                           // 512
    size_t o_Pp   = o_hcw2 + 512;                            // 16384*104*4 = 6.8MB
    size_t o_qs   = o_Pp + (size_t)BATCH * 104 * 4;          // 2MB

    f16*   states16 = (f16*)(ws + o_states16);
    f16*   W1t      = (f16*)(ws + o_W1t);
    float* b1cat    = (float*)(ws + o_b1);
    f16*   W2t      = (f16*)(ws + o_W2t);
    f16*   hcw2     = (f16*)(ws + o_hcw2);
    float* Pp       = (float*)(ws + o_Pp);
    float* qs_tot   = (float*)(ws + o_qs);

    k_main<<<NB_MAIN, 256, 0, stream>>>(
        agent_qs, states, indiv_us, edge_W, edge_b, wline1, wline2,
        hw1_w1, hc1_w1, hw_w1, hc_w1, hw1_b1, hc1_b1, hw_b1, hc_b1,
        hw1_w2, hc1_w2, hw_w2, hc_w2,
        states16, W1t, b1cat, W2t, hcw2, qs_tot);
    k_gemm<<<256, 512, 0, stream>>>(states16, W1t, b1cat, W2t, hcw2, Pp);
    k_ep<<<BATCH / 32, 256, 0, stream>>>(Pp, qs_tot, hw1_b2, hc1_b2, hw_b2, hc_b2,
                                         (float*)d_out);
}